// Round 12
// baseline (290.049 us; speedup 1.0000x reference)
//
#include <hip/hip_runtime.h>
#include <stdint.h>

// Qatten_Weight — Round 12: RESUBMIT of Round 11 (bench infra failed, no data).
// Double-M per wave (B-reuse 2x). Model (R4..R10): runtime ~ B-fragment bytes
// delivered per CU; LDS staging doesn't reduce bytes, register reuse does.
// Each wave holds BOTH M-tiles' A-frags (aFA/aFB, 128 VGPR) and owns an
// N-QUARTER; every B-frag load feeds 2 MFMAs -> P1 L2 traffic 1GB -> 512MB.
// __launch_bounds__(256,2) caps VGPR at 256 (est ~215; watch WRITE_SIZE).
// B=16384 A=8 S=512 U=64 H=4 E=64 HE=256; BT=32, grid 512 x 256 threads.

typedef __attribute__((ext_vector_type(8))) short short8v;  // 8 bf16
typedef __attribute__((ext_vector_type(4))) float f32x4;

constexpr int BB = 16384, AA = 8, SS = 512, UU = 64, HH = 4, EE = 64, HE = 256;
constexpr int BT = 32;
constexpr int OUTV = BB * AA, OUTR = OUTV + BB, OUTE = OUTR + 1;

// packed fragment regions in ws (bf16 element offsets); frag = 512 elems = 1KB
constexpr int OFF_W1F  = 0;        // sel_w1: frag = h*256 + ftile*16 + kf   (1024)
constexpr int OFF_W2F  = 524288;   // sel_w2: frag = h*32  + etile*8  + kf   (128)
constexpr int OFF_VW1F = 589824;   // v_w1:   frag = etile*16 + kf           (64)
constexpr int OFF_KWF  = 622592;   // key_w:  frag = h*8 + utile*2 + kf      (32)
constexpr int PREP_N   = 638976;

__device__ __forceinline__ unsigned short f2bf(float x) {
  union { float f; uint32_t u; } v; v.f = x;
  uint32_t r = v.u + 0x7fffu + ((v.u >> 16) & 1u);   // RNE
  return (unsigned short)(r >> 16);
}
__device__ __forceinline__ float bf2f(short h) {
  union { uint32_t u; float f; } v; v.u = ((uint32_t)(unsigned short)h) << 16;
  return v.f;
}

// Pack: within a frag, element r = l*8 + j holds B[k = kf*32 + (l>>4)*8 + j]
// [col = tile*16 + (l&15)] — exactly the 16x16x32 B-fragment lane layout.
__global__ __launch_bounds__(256) void prep_kernel(
    const float* __restrict__ w1, const float* __restrict__ w2,
    const float* __restrict__ vw1, const float* __restrict__ kw,
    unsigned short* __restrict__ ws) {
  int idx = blockIdx.x * 256 + threadIdx.x;
  if (idx >= PREP_N) return;
  int r = idx & 511, l = r >> 3, j = r & 7, lr = l & 15, g = l >> 4;
  int fi = idx >> 9;
  float val;
  if (idx < OFF_W2F) {                    // B[k=s][col=f] for P1
    int h = fi >> 8, tl = (fi >> 4) & 15, kf = fi & 15;
    int s = kf * 32 + g * 8 + j, f = tl * 16 + lr;
    val = w1[((size_t)(h * SS) + s) * HE + f];
  } else if (idx < OFF_VW1F) {            // B[k=f][col=e] for P2
    fi -= OFF_W2F >> 9;
    int h = fi >> 5, tl = (fi >> 3) & 3, kf = fi & 7;
    int k = kf * 32 + g * 8 + j, e = tl * 16 + lr;
    val = w2[((size_t)(h * HE) + k) * EE + e];
  } else if (idx < OFF_KWF) {             // B[k=s][col=e] for P1v
    fi -= OFF_VW1F >> 9;
    int tl = fi >> 4, kf = fi & 15;
    int s = kf * 32 + g * 8 + j, e = tl * 16 + lr;
    val = vw1[(size_t)s * EE + e];
  } else {                                // B[k=e][col=u] for P3
    fi -= OFF_KWF >> 9;
    int h = fi >> 3, tl = (fi >> 1) & 3, kf = fi & 1;
    int k = kf * 32 + g * 8 + j, u = tl * 16 + lr;
    val = kw[((size_t)(h * UU) + u) * EE + k];
  }
  ws[idx] = f2bf(val);
}

__global__ __launch_bounds__(256, 2) void qatten_mfma(
    const float* __restrict__ states, const float* __restrict__ sel_b1,
    const float* __restrict__ v_b1,  const float* __restrict__ v_w2,
    const float* __restrict__ v_b2,  const unsigned short* __restrict__ ws,
    float* __restrict__ out) {
  __shared__ __align__(16) unsigned char lds[39168];
  short* hmid = (short*)lds;                 // [32][264] bf16  (16896 B)
  short* sel  = (short*)(lds + 16896);       // [32][72]  bf16  ( 4608 B)
  short* mh   = (short*)(lds + 21504);       // [32][72]  bf16  ( 4608 B)
  short* vhid = (short*)(lds + 26112);       // [32][72]  bf16  ( 4608 B)
  float* logitsL = (float*)(lds + 30720);    // [32][33] f32    ( 4224 B)
  float* wtsL    = (float*)(lds + 34944);    // [32][33] f32    ( 4224 B)

  const int t  = threadIdx.x;
  const int nq = t >> 6;                     // wave id = N-QUARTER (0..3)
  const int l  = t & 63;
  const int lr = l & 15, g = l >> 4;
  const int b0 = blockIdx.x * BT;
  const short* w1f  = (const short*)ws + OFF_W1F;
  const short* w2f  = (const short*)ws + OFF_W2F;
  const short* vw1f = (const short*)ws + OFF_VW1F;
  const short* kwf  = (const short*)ws + OFF_KWF;

  // ---- A-fragments: BOTH M-tiles per wave (rows lr and 16+lr) ----
  short8v aFA[16], aFB[16];
  {
    const float* srowA = states + (size_t)(b0 + lr) * (AA * SS);
    const float* srowB = states + (size_t)(b0 + 16 + lr) * (AA * SS);
    #pragma unroll
    for (int f = 0; f < 16; ++f) {
      float4 p0 = *(const float4*)(srowA + f * 32 + g * 8);
      float4 p1 = *(const float4*)(srowA + f * 32 + g * 8 + 4);
      short8v a;
      a[0] = (short)f2bf(p0.x); a[1] = (short)f2bf(p0.y);
      a[2] = (short)f2bf(p0.z); a[3] = (short)f2bf(p0.w);
      a[4] = (short)f2bf(p1.x); a[5] = (short)f2bf(p1.y);
      a[6] = (short)f2bf(p1.z); a[7] = (short)f2bf(p1.w);
      aFA[f] = a;
      float4 q0 = *(const float4*)(srowB + f * 32 + g * 8);
      float4 q1 = *(const float4*)(srowB + f * 32 + g * 8 + 4);
      short8v b;
      b[0] = (short)f2bf(q0.x); b[1] = (short)f2bf(q0.y);
      b[2] = (short)f2bf(q0.z); b[3] = (short)f2bf(q0.w);
      b[4] = (short)f2bf(q1.x); b[5] = (short)f2bf(q1.y);
      b[6] = (short)f2bf(q1.z); b[7] = (short)f2bf(q1.w);
      aFB[f] = b;
    }
  }

  for (int h = 0; h < HH; ++h) {
    // ---- P1: hmid = relu(st @ sel_w1[h] + b1); wave = 4 f-tiles x 2 mt ----
    f32x4 acc[2][4] = {{{0,0,0,0},{0,0,0,0},{0,0,0,0},{0,0,0,0}},
                       {{0,0,0,0},{0,0,0,0},{0,0,0,0},{0,0,0,0}}};
    {
      const short* bb = w1f + ((size_t)(h * 256 + nq * 64)) * 512 + l * 8;
      #pragma unroll
      for (int kf = 0; kf < 16; ++kf) {
        #pragma unroll
        for (int tl = 0; tl < 4; ++tl) {
          short8v bf = *(const short8v*)(bb + (size_t)(tl * 16 + kf) * 512);
          acc[0][tl] = __builtin_amdgcn_mfma_f32_16x16x32_bf16(
              aFA[kf], bf, acc[0][tl], 0, 0, 0);
          acc[1][tl] = __builtin_amdgcn_mfma_f32_16x16x32_bf16(
              aFB[kf], bf, acc[1][tl], 0, 0, 0);
        }
      }
    }
    #pragma unroll
    for (int tl = 0; tl < 4; ++tl) {
      int fb = (nq * 4 + tl) * 16;
      float bias = sel_b1[h * HE + fb + lr];
      #pragma unroll
      for (int mt = 0; mt < 2; ++mt)
        #pragma unroll
        for (int r2 = 0; r2 < 4; ++r2)
          hmid[(mt * 16 + g * 4 + r2) * 264 + fb + lr] =
              (short)f2bf(fmaxf(acc[mt][tl][r2] + bias, 0.f));
    }
    __syncthreads();

    // ---- P2: sel = hmid @ sel_w2[h]; wave = e-tile nq x 2 mt, K=256 ----
    f32x4 a2[2] = {{0,0,0,0},{0,0,0,0}};
    {
      const short* ahA = hmid + lr * 264 + g * 8;
      const short* ahB = hmid + (16 + lr) * 264 + g * 8;
      const short* b2 = w2f + ((size_t)(h * 32 + nq * 8)) * 512 + l * 8;
      #pragma unroll
      for (int kf = 0; kf < 8; ++kf) {
        short8v bf = *(const short8v*)(b2 + (size_t)kf * 512);
        a2[0] = __builtin_amdgcn_mfma_f32_16x16x32_bf16(
            *(const short8v*)(ahA + kf * 32), bf, a2[0], 0, 0, 0);
        a2[1] = __builtin_amdgcn_mfma_f32_16x16x32_bf16(
            *(const short8v*)(ahB + kf * 32), bf, a2[1], 0, 0, 0);
      }
    }
    #pragma unroll
    for (int mt = 0; mt < 2; ++mt)
      #pragma unroll
      for (int r2 = 0; r2 < 4; ++r2)
        sel[(mt * 16 + g * 4 + r2) * 72 + nq * 16 + lr] =
            (short)f2bf(a2[mt][r2]);
    __syncthreads();

    // ---- P3: m = sel @ key_w[h]^T; wave = u-tile nq x 2 mt, K=64 ----
    f32x4 a3[2] = {{0,0,0,0},{0,0,0,0}};
    {
      const short* asA = sel + lr * 72 + g * 8;
      const short* asB = sel + (16 + lr) * 72 + g * 8;
      const short* b3 = kwf + ((size_t)(h * 8 + nq * 2)) * 512 + l * 8;
      #pragma unroll
      for (int kf = 0; kf < 2; ++kf) {
        short8v bf = *(const short8v*)(b3 + (size_t)kf * 512);
        a3[0] = __builtin_amdgcn_mfma_f32_16x16x32_bf16(
            *(const short8v*)(asA + kf * 32), bf, a3[0], 0, 0, 0);
        a3[1] = __builtin_amdgcn_mfma_f32_16x16x32_bf16(
            *(const short8v*)(asB + kf * 32), bf, a3[1], 0, 0, 0);
      }
    }
    #pragma unroll
    for (int mt = 0; mt < 2; ++mt)
      #pragma unroll
      for (int r2 = 0; r2 < 4; ++r2)
        mh[(mt * 16 + g * 4 + r2) * 72 + nq * 16 + lr] =
            (short)f2bf(a3[mt][r2]);
    __syncthreads();

    // ---- P4h: logits from registers for BOTH rows (static aF indices) ----
    {
      const short* mrowA = mh + lr * 72;
      const short* mrowB = mh + (16 + lr) * 72;
      short8v mvA0 = *(const short8v*)(mrowA + g * 8);
      short8v mvA1 = *(const short8v*)(mrowA + 32 + g * 8);
      short8v mvB0 = *(const short8v*)(mrowB + g * 8);
      short8v mvB1 = *(const short8v*)(mrowB + 32 + g * 8);
      #pragma unroll
      for (int a = 0; a < 8; ++a) {        // compile-time constant
        short8v aA0 = aFA[a * 2], aA1 = aFA[a * 2 + 1];
        short8v aB0 = aFB[a * 2], aB1 = aFB[a * 2 + 1];
        float pA = 0.f, pB = 0.f;
        #pragma unroll
        for (int j = 0; j < 8; ++j) {
          pA += bf2f(aA0[j]) * bf2f(mvA0[j]) + bf2f(aA1[j]) * bf2f(mvA1[j]);
          pB += bf2f(aB0[j]) * bf2f(mvB0[j]) + bf2f(aB1[j]) * bf2f(mvB1[j]);
        }
        pA += __shfl_xor(pA, 16); pA += __shfl_xor(pA, 32);
        pB += __shfl_xor(pB, 16); pB += __shfl_xor(pB, 32);
        if (g == 0 && (a >> 1) == nq) {
          logitsL[lr * 33 + h * 8 + a] = pA;
          logitsL[(16 + lr) * 33 + h * 8 + a] = pB;
        }
      }
    }
    // no barrier: next P1 writes hmid (last read 2 barriers ago); mh next
    // written by next P3 (2 barriers away); logitsL read only in P5.
  }

  // ---- P1v: vhid = relu(st @ v_w1 + b1); wave = e-tile nq x 2 mt ----
  {
    f32x4 av[2] = {{0,0,0,0},{0,0,0,0}};
    const short* bv = vw1f + ((size_t)(nq * 16)) * 512 + l * 8;
    #pragma unroll
    for (int kf = 0; kf < 16; ++kf) {
      short8v bf = *(const short8v*)(bv + (size_t)kf * 512);
      av[0] = __builtin_amdgcn_mfma_f32_16x16x32_bf16(aFA[kf], bf, av[0], 0, 0, 0);
      av[1] = __builtin_amdgcn_mfma_f32_16x16x32_bf16(aFB[kf], bf, av[1], 0, 0, 0);
    }
    float bias = v_b1[nq * 16 + lr];
    #pragma unroll
    for (int mt = 0; mt < 2; ++mt)
      #pragma unroll
      for (int r2 = 0; r2 < 4; ++r2)
        vhid[(mt * 16 + g * 4 + r2) * 72 + nq * 16 + lr] =
            (short)f2bf(fmaxf(av[mt][r2] + bias, 0.f));
  }
  __syncthreads();

  // ---- v finalize (reads vhid) ----
  {
    int b = t >> 3, r = t & 7;
    short8v hv = *(const short8v*)(vhid + b * 72 + r * 8);
    float p = 0.f;
    #pragma unroll
    for (int j = 0; j < 8; ++j) p += bf2f(hv[j]) * v_w2[r * 8 + j];
    p += __shfl_xor(p, 1); p += __shfl_xor(p, 2); p += __shfl_xor(p, 4);
    if (r == 0) out[OUTV + b0 + b] = p + v_b2[0];
  }
  __syncthreads();

  // ---- P5: softmax, entropy, reg (R7 verbatim) ----
  if (t < 128) {
    int b = t >> 2, hh = t & 3;
    float sc[8];
    float rp = 0.f, mx = -1e30f;
    #pragma unroll
    for (int a = 0; a < 8; ++a) {
      float lg = logitsL[b * 33 + hh * 8 + a];
      rp += lg * lg;
      sc[a] = lg * 0.125f;
      mx = fmaxf(mx, sc[a]);
    }
    float sum = 0.f;
    #pragma unroll
    for (int a = 0; a < 8; ++a) { sc[a] = __expf(sc[a] - mx); sum += sc[a]; }
    float inv = 1.f / sum, ent = 0.f;
    #pragma unroll
    for (int a = 0; a < 8; ++a) {
      float wv = sc[a] * inv;
      wtsL[b * 33 + hh * 8 + a] = wv;
      ent += wv * __logf(wv + 1e-8f);
    }
    #pragma unroll
    for (int off = 1; off <= 32; off <<= 1) rp += __shfl_xor(rp, off);
    if ((t & 63) == 0)
      atomicAdd(out + OUTR, rp * (0.001f / ((float)BB * (float)AA)));
    float ep = ent;
    #pragma unroll
    for (int off = 4; off <= 32; off <<= 1) ep += __shfl_xor(ep, off);
    if ((t & 63) < 4) atomicAdd(out + OUTE + hh, -ep / (float)BB);
  }
  __syncthreads();
  {
    int b = t >> 3, a = t & 7;
    out[(size_t)(b0 + b) * AA + a] = wtsL[b * 33 + a] + wtsL[b * 33 + 8 + a] +
                                     wtsL[b * 33 + 16 + a] + wtsL[b * 33 + 24 + a];
  }
}

extern "C" void kernel_launch(void* const* d_in, const int* in_sizes, int n_in,
                              void* d_out, int out_size, void* d_ws, size_t ws_size,
                              hipStream_t stream) {
  (void)in_sizes; (void)n_in; (void)ws_size; (void)out_size;
  const float* states = (const float*)d_in[1];
  const float* sel_w1 = (const float*)d_in[3];
  const float* sel_b1 = (const float*)d_in[4];
  const float* sel_w2 = (const float*)d_in[5];
  const float* key_w  = (const float*)d_in[6];
  const float* v_w1   = (const float*)d_in[7];
  const float* v_b1   = (const float*)d_in[8];
  const float* v_w2   = (const float*)d_in[9];
  const float* v_b2   = (const float*)d_in[10];
  float* out = (float*)d_out;
  unsigned short* ws = (unsigned short*)d_ws;

  hipMemsetAsync(out + OUTR, 0, 5 * sizeof(float), stream);
  prep_kernel<<<(PREP_N + 255) / 256, 256, 0, stream>>>(sel_w1, sel_w2, v_w1,
                                                        key_w, ws);
  qatten_mfma<<<BB / BT, 256, 0, stream>>>(states, sel_b1, v_b1, v_w2, v_b2,
                                           ws, out);
}

// Round 13
// 160.261 us; speedup vs baseline: 1.8099x; 1.8099x over previous
//
#include <hip/hip_runtime.h>
#include <stdint.h>

// Qatten_Weight — Round 13: occupancy 2x via 8-wave blocks.
// R4..R12 model: latency-bound at ~4x the L2-BW floor; waves/SIMD is the
// unexploited lever (grid 512 x 4-wave blocks = only 2 waves/SIMD). Now:
// 512 threads (8 waves = 2 M-tiles x 4 N-quarters), BT=32, grid 512,
// R7's 39KB LDS -> 2 blocks/CU x 8 waves = 4 waves/SIMD. B-traffic and
// per-SIMD outstanding loads unchanged; VGPR ~128 (no spill risk).
// R3's NaN is explained (72KB static LDS > 64KB limit), this stays at 39KB.
// B=16384 A=8 S=512 U=64 H=4 E=64 HE=256; grid 512 x 512 threads.

typedef __attribute__((ext_vector_type(8))) short short8v;  // 8 bf16
typedef __attribute__((ext_vector_type(4))) float f32x4;

constexpr int BB = 16384, AA = 8, SS = 512, UU = 64, HH = 4, EE = 64, HE = 256;
constexpr int BT = 32;
constexpr int OUTV = BB * AA, OUTR = OUTV + BB, OUTE = OUTR + 1;

// packed fragment regions in ws (bf16 element offsets); frag = 512 elems = 1KB
constexpr int OFF_W1F  = 0;        // sel_w1: frag = h*256 + ftile*16 + kf   (1024)
constexpr int OFF_W2F  = 524288;   // sel_w2: frag = h*32  + etile*8  + kf   (128)
constexpr int OFF_VW1F = 589824;   // v_w1:   frag = etile*16 + kf           (64)
constexpr int OFF_KWF  = 622592;   // key_w:  frag = h*8 + utile*2 + kf      (32)
constexpr int PREP_N   = 638976;

__device__ __forceinline__ unsigned short f2bf(float x) {
  union { float f; uint32_t u; } v; v.f = x;
  uint32_t r = v.u + 0x7fffu + ((v.u >> 16) & 1u);   // RNE
  return (unsigned short)(r >> 16);
}
__device__ __forceinline__ float bf2f(short h) {
  union { uint32_t u; float f; } v; v.u = ((uint32_t)(unsigned short)h) << 16;
  return v.f;
}

// Pack: within a frag, element r = l*8 + j holds B[k = kf*32 + (l>>4)*8 + j]
// [col = tile*16 + (l&15)] — exactly the 16x16x32 B-fragment lane layout.
__global__ __launch_bounds__(256) void prep_kernel(
    const float* __restrict__ w1, const float* __restrict__ w2,
    const float* __restrict__ vw1, const float* __restrict__ kw,
    unsigned short* __restrict__ ws) {
  int idx = blockIdx.x * 256 + threadIdx.x;
  if (idx >= PREP_N) return;
  int r = idx & 511, l = r >> 3, j = r & 7, lr = l & 15, g = l >> 4;
  int fi = idx >> 9;
  float val;
  if (idx < OFF_W2F) {                    // B[k=s][col=f] for P1
    int h = fi >> 8, tl = (fi >> 4) & 15, kf = fi & 15;
    int s = kf * 32 + g * 8 + j, f = tl * 16 + lr;
    val = w1[((size_t)(h * SS) + s) * HE + f];
  } else if (idx < OFF_VW1F) {            // B[k=f][col=e] for P2
    fi -= OFF_W2F >> 9;
    int h = fi >> 5, tl = (fi >> 3) & 3, kf = fi & 7;
    int k = kf * 32 + g * 8 + j, e = tl * 16 + lr;
    val = w2[((size_t)(h * HE) + k) * EE + e];
  } else if (idx < OFF_KWF) {             // B[k=s][col=e] for P1v
    fi -= OFF_VW1F >> 9;
    int tl = fi >> 4, kf = fi & 15;
    int s = kf * 32 + g * 8 + j, e = tl * 16 + lr;
    val = vw1[(size_t)s * EE + e];
  } else {                                // B[k=e][col=u] for P3
    fi -= OFF_KWF >> 9;
    int h = fi >> 3, tl = (fi >> 1) & 3, kf = fi & 1;
    int k = kf * 32 + g * 8 + j, u = tl * 16 + lr;
    val = kw[((size_t)(h * UU) + u) * EE + k];
  }
  ws[idx] = f2bf(val);
}

__global__ __launch_bounds__(512) void qatten_mfma(
    const float* __restrict__ states, const float* __restrict__ sel_b1,
    const float* __restrict__ v_b1,  const float* __restrict__ v_w2,
    const float* __restrict__ v_b2,  const unsigned short* __restrict__ ws,
    float* __restrict__ out) {
  __shared__ __align__(16) unsigned char lds[39168];
  short* hmid = (short*)lds;                 // [32][264] bf16  (16896 B)
  short* sel  = (short*)(lds + 16896);       // [32][72]  bf16  ( 4608 B)
  short* mh   = (short*)(lds + 21504);       // [32][72]  bf16  ( 4608 B)
  short* vhid = (short*)(lds + 26112);       // [32][72]  bf16  ( 4608 B)
  float* logitsL = (float*)(lds + 30720);    // [32][33] f32    ( 4224 B)
  float* wtsL    = (float*)(lds + 34944);    // [32][33] f32    ( 4224 B)

  const int t  = threadIdx.x;
  const int w  = t >> 6, l = t & 63;
  const int mt = w & 1, nq = w >> 1;         // M-tile (2), N-quarter (4)
  const int lr = l & 15, g = l >> 4;
  const int b0 = blockIdx.x * BT;
  const short* w1f  = (const short*)ws + OFF_W1F;
  const short* w2f  = (const short*)ws + OFF_W2F;
  const short* vw1f = (const short*)ws + OFF_VW1F;
  const short* kwf  = (const short*)ws + OFF_KWF;

  // ---- A-fragments: 16 rows of st for this wave's M-tile (64 VGPR) ----
  short8v aF[16];
  {
    const float* srow = states + (size_t)(b0 + mt * 16 + lr) * (AA * SS);
    #pragma unroll
    for (int f = 0; f < 16; ++f) {
      float4 p0 = *(const float4*)(srow + f * 32 + g * 8);
      float4 p1 = *(const float4*)(srow + f * 32 + g * 8 + 4);
      short8v a;
      a[0] = (short)f2bf(p0.x); a[1] = (short)f2bf(p0.y);
      a[2] = (short)f2bf(p0.z); a[3] = (short)f2bf(p0.w);
      a[4] = (short)f2bf(p1.x); a[5] = (short)f2bf(p1.y);
      a[6] = (short)f2bf(p1.z); a[7] = (short)f2bf(p1.w);
      aF[f] = a;
    }
  }

  for (int h = 0; h < HH; ++h) {
    // ---- P1: hmid = relu(st @ sel_w1[h] + b1); 4 f-tiles, 4 indep accs ----
    f32x4 acc[4] = {{0,0,0,0},{0,0,0,0},{0,0,0,0},{0,0,0,0}};
    {
      const short* bb = w1f + ((size_t)(h * 256 + nq * 64)) * 512 + l * 8;
      #pragma unroll
      for (int kf = 0; kf < 16; ++kf) {
        short8v af = aF[kf];
        #pragma unroll
        for (int tl = 0; tl < 4; ++tl)
          acc[tl] = __builtin_amdgcn_mfma_f32_16x16x32_bf16(
              af, *(const short8v*)(bb + (size_t)(tl * 16 + kf) * 512),
              acc[tl], 0, 0, 0);
      }
    }
    #pragma unroll
    for (int tl = 0; tl < 4; ++tl) {
      int fb = (nq * 4 + tl) * 16;
      float bias = sel_b1[h * HE + fb + lr];
      #pragma unroll
      for (int r2 = 0; r2 < 4; ++r2)
        hmid[(mt * 16 + g * 4 + r2) * 264 + fb + lr] =
            (short)f2bf(fmaxf(acc[tl][r2] + bias, 0.f));
    }
    __syncthreads();

    // ---- P2: sel = hmid @ sel_w2[h]; wave = e-tile nq, K=256 ----
    f32x4 a2 = {0, 0, 0, 0};
    {
      const short* ah = hmid + (mt * 16 + lr) * 264 + g * 8;
      const short* b2 = w2f + ((size_t)(h * 32 + nq * 8)) * 512 + l * 8;
      #pragma unroll
      for (int kf = 0; kf < 8; ++kf)
        a2 = __builtin_amdgcn_mfma_f32_16x16x32_bf16(
            *(const short8v*)(ah + kf * 32),
            *(const short8v*)(b2 + (size_t)kf * 512), a2, 0, 0, 0);
    }
    #pragma unroll
    for (int r2 = 0; r2 < 4; ++r2)
      sel[(mt * 16 + g * 4 + r2) * 72 + nq * 16 + lr] = (short)f2bf(a2[r2]);
    __syncthreads();

    // ---- P3: m = sel @ key_w[h]^T; wave = u-tile nq, K=64 ----
    f32x4 a3 = {0, 0, 0, 0};
    {
      const short* as = sel + (mt * 16 + lr) * 72 + g * 8;
      const short* b3 = kwf + ((size_t)(h * 8 + nq * 2)) * 512 + l * 8;
      #pragma unroll
      for (int kf = 0; kf < 2; ++kf)
        a3 = __builtin_amdgcn_mfma_f32_16x16x32_bf16(
            *(const short8v*)(as + kf * 32),
            *(const short8v*)(b3 + (size_t)kf * 512), a3, 0, 0, 0);
    }
    #pragma unroll
    for (int r2 = 0; r2 < 4; ++r2)
      mh[(mt * 16 + g * 4 + r2) * 72 + nq * 16 + lr] = (short)f2bf(a3[r2]);
    __syncthreads();

    // ---- P4h: logits from registers (static aF indices; R6/R7-proven) ----
    {
      const short* mrow = mh + (mt * 16 + lr) * 72;
      short8v mv0 = *(const short8v*)(mrow + g * 8);
      short8v mv1 = *(const short8v*)(mrow + 32 + g * 8);
      #pragma unroll
      for (int a = 0; a < 8; ++a) {        // compile-time constant
        short8v a0 = aF[a * 2], a1 = aF[a * 2 + 1];
        float p = 0.f;
        #pragma unroll
        for (int j = 0; j < 8; ++j)
          p += bf2f(a0[j]) * bf2f(mv0[j]) + bf2f(a1[j]) * bf2f(mv1[j]);
        p += __shfl_xor(p, 16);
        p += __shfl_xor(p, 32);
        if (g == 0 && (a >> 1) == nq)       // wave nq owns agents 2nq,2nq+1
          logitsL[(mt * 16 + lr) * 33 + h * 8 + a] = p;
      }
    }
    // no barrier: next P1 writes hmid (last read before the P2 barrier);
    // mh next written by next P3 (2 barriers away); logitsL read in P5 only.
  }

  // ---- P1v: vhid = relu(st @ v_w1 + b1); wave = e-tile nq ----
  {
    f32x4 av = {0, 0, 0, 0};
    const short* bv = vw1f + ((size_t)(nq * 16)) * 512 + l * 8;
    #pragma unroll
    for (int kf = 0; kf < 16; ++kf)
      av = __builtin_amdgcn_mfma_f32_16x16x32_bf16(
          aF[kf], *(const short8v*)(bv + (size_t)kf * 512), av, 0, 0, 0);
    float bias = v_b1[nq * 16 + lr];
    #pragma unroll
    for (int r2 = 0; r2 < 4; ++r2)
      vhid[(mt * 16 + g * 4 + r2) * 72 + nq * 16 + lr] =
          (short)f2bf(fmaxf(av[r2] + bias, 0.f));
  }
  __syncthreads();

  // ---- v finalize (reads vhid): threads 0..255 = 32 rows x 8 ----
  if (t < 256) {
    int b = t >> 3, r = t & 7;
    short8v hv = *(const short8v*)(vhid + b * 72 + r * 8);
    float p = 0.f;
    #pragma unroll
    for (int j = 0; j < 8; ++j) p += bf2f(hv[j]) * v_w2[r * 8 + j];
    p += __shfl_xor(p, 1); p += __shfl_xor(p, 2); p += __shfl_xor(p, 4);
    if (r == 0) out[OUTV + b0 + b] = p + v_b2[0];
  }
  __syncthreads();

  // ---- P5: softmax, entropy, reg (R7 verbatim; threads 0..127) ----
  if (t < 128) {
    int b = t >> 2, hh = t & 3;
    float sc[8];
    float rp = 0.f, mx = -1e30f;
    #pragma unroll
    for (int a = 0; a < 8; ++a) {
      float lg = logitsL[b * 33 + hh * 8 + a];
      rp += lg * lg;
      sc[a] = lg * 0.125f;
      mx = fmaxf(mx, sc[a]);
    }
    float sum = 0.f;
    #pragma unroll
    for (int a = 0; a < 8; ++a) { sc[a] = __expf(sc[a] - mx); sum += sc[a]; }
    float inv = 1.f / sum, ent = 0.f;
    #pragma unroll
    for (int a = 0; a < 8; ++a) {
      float wv = sc[a] * inv;
      wtsL[b * 33 + hh * 8 + a] = wv;
      ent += wv * __logf(wv + 1e-8f);
    }
    #pragma unroll
    for (int off = 1; off <= 32; off <<= 1) rp += __shfl_xor(rp, off);
    if ((t & 63) == 0)
      atomicAdd(out + OUTR, rp * (0.001f / ((float)BB * (float)AA)));
    float ep = ent;
    #pragma unroll
    for (int off = 4; off <= 32; off <<= 1) ep += __shfl_xor(ep, off);
    if ((t & 63) < 4) atomicAdd(out + OUTE + hh, -ep / (float)BB);
  }
  __syncthreads();
  if (t < 256) {
    int b = t >> 3, a = t & 7;
    out[(size_t)(b0 + b) * AA + a] = wtsL[b * 33 + a] + wtsL[b * 33 + 8 + a] +
                                     wtsL[b * 33 + 16 + a] + wtsL[b * 33 + 24 + a];
  }
}

extern "C" void kernel_launch(void* const* d_in, const int* in_sizes, int n_in,
                              void* d_out, int out_size, void* d_ws, size_t ws_size,
                              hipStream_t stream) {
  (void)in_sizes; (void)n_in; (void)ws_size; (void)out_size;
  const float* states = (const float*)d_in[1];
  const float* sel_w1 = (const float*)d_in[3];
  const float* sel_b1 = (const float*)d_in[4];
  const float* sel_w2 = (const float*)d_in[5];
  const float* key_w  = (const float*)d_in[6];
  const float* v_w1   = (const float*)d_in[7];
  const float* v_b1   = (const float*)d_in[8];
  const float* v_w2   = (const float*)d_in[9];
  const float* v_b2   = (const float*)d_in[10];
  float* out = (float*)d_out;
  unsigned short* ws = (unsigned short*)d_ws;

  hipMemsetAsync(out + OUTR, 0, 5 * sizeof(float), stream);
  prep_kernel<<<(PREP_N + 255) / 256, 256, 0, stream>>>(sel_w1, sel_w2, v_w1,
                                                        key_w, ws);
  qatten_mfma<<<BB / BT, 512, 0, stream>>>(states, sel_b1, v_b1, v_w2, v_b2,
                                           ws, out);
}